// Round 2
// baseline (164.373 us; speedup 1.0000x reference)
//
#include <hip/hip_runtime.h>

#define H 512
#define W 512
#define NIMG 8
#define TS 64            // output tile edge
#define RD 127           // LDS row stride in floats (odd -> conflict-free col access)
#define NE 124           // energy region edge (64 + 2*30)
#define NR 126           // raw staging region edge (NE + 2)

// zero-padded global load ('SAME' conv padding)
__device__ __forceinline__ float ldz(const float* __restrict__ p, int y, int x) {
    return ((unsigned)y < (unsigned)H && (unsigned)x < (unsigned)W) ? p[y * W + x] : 0.0f;
}

// Sobel (cross-correlation, matches lax.conv):
__device__ __forceinline__ void sobel_g(const float* __restrict__ p, int y, int x,
                                        float& gx, float& gy) {
    float a00 = ldz(p, y - 1, x - 1), a01 = ldz(p, y - 1, x), a02 = ldz(p, y - 1, x + 1);
    float a10 = ldz(p, y,     x - 1),                          a12 = ldz(p, y,     x + 1);
    float a20 = ldz(p, y + 1, x - 1), a21 = ldz(p, y + 1, x), a22 = ldz(p, y + 1, x + 1);
    gx = (a02 - a00) + 2.0f * (a12 - a10) + (a22 - a20);
    gy = (a20 - a00) + 2.0f * (a21 - a01) + (a22 - a02);
}

// inclusive wave-scan (64 lanes)
__device__ __forceinline__ float wscan(float x, int lane) {
    #pragma unroll
    for (int off = 1; off < 64; off <<= 1) {
        float t = __shfl_up(x, off, 64);
        if (lane >= off) x += t;
    }
    return x;
}

__global__ __launch_bounds__(1024, 4) void k_tile(const float* __restrict__ v,
                                                  const float* __restrict__ i_,
                                                  const float* __restrict__ img,
                                                  double* __restrict__ partials) {
    __shared__ float Sv[RD * RD];     // raw v -> energy E_v -> exclusive SAT of E_v
    __shared__ float Si[RD * RD];     // raw i -> energy E_i -> exclusive SAT of E_i
    __shared__ double red[16];

    const int tid  = threadIdx.x;
    const int lane = tid & 63;
    const int wid  = tid >> 6;
    const int tx = blockIdx.x, ty = blockIdx.y, n = blockIdx.z;
    const int bx = tx * TS - 30, by = ty * TS - 30;   // energy-region origin (global)
    const float* pv = v   + (size_t)n * (H * W);
    const float* pi = i_  + (size_t)n * (H * W);
    const float* pf = img + (size_t)n * (H * W);

    const int col  = tid & 127;     // 0..127
    const int rw0  = tid >> 7;      // 0..7

    // ---- 1. stage raw v,i: LDS[r][c] = src(by-1+r, bx-1+c), r,c in [0,126)
    #pragma unroll
    for (int jb = 0; jb < 16; ++jb) {
        int r = jb * 8 + rw0;
        if (r < NR && col < NR) {
            int gy = by - 1 + r, gx = bx - 1 + col;
            bool in = ((unsigned)gy < (unsigned)H) && ((unsigned)gx < (unsigned)W);
            size_t off = (size_t)gy * W + gx;
            Sv[r * RD + col] = in ? pv[off] : 0.0f;
            Si[r * RD + col] = in ? pi[off] : 0.0f;
        }
    }
    __syncthreads();

    // ---- 2. energies from LDS raw into registers
    float ev[16], ei[16];
    #pragma unroll
    for (int jb = 0; jb < 16; ++jb) {
        int j = jb * 8 + rw0;
        ev[jb] = 0.0f; ei[jb] = 0.0f;
        if (j < NE && col < NE) {
            {
                const float* r0 = Sv + j * RD + col;
                float a00 = r0[0],      a01 = r0[1],        a02 = r0[2];
                float a10 = r0[RD],                          a12 = r0[RD + 2];
                float a20 = r0[2 * RD], a21 = r0[2 * RD + 1], a22 = r0[2 * RD + 2];
                float gx = (a02 - a00) + 2.0f * (a12 - a10) + (a22 - a20);
                float gy = (a20 - a00) + 2.0f * (a21 - a01) + (a22 - a02);
                ev[jb] = gx * gx + gy * gy;
            }
            {
                const float* r0 = Si + j * RD + col;
                float a00 = r0[0],      a01 = r0[1],        a02 = r0[2];
                float a10 = r0[RD],                          a12 = r0[RD + 2];
                float a20 = r0[2 * RD], a21 = r0[2 * RD + 1], a22 = r0[2 * RD + 2];
                float gx = (a02 - a00) + 2.0f * (a12 - a10) + (a22 - a20);
                float gy = (a20 - a00) + 2.0f * (a21 - a01) + (a22 - a02);
                ei[jb] = gx * gx + gy * gy;
            }
        }
    }
    __syncthreads();

    // ---- 3. write energies at [1+j][1+c]; zero SAT row 0 / col 0
    #pragma unroll
    for (int jb = 0; jb < 16; ++jb) {
        int j = jb * 8 + rw0;
        if (j < NE && col < NE) {
            Sv[(1 + j) * RD + 1 + col] = ev[jb];
            Si[(1 + j) * RD + 1 + col] = ei[jb];
        }
    }
    if (tid <= NE) {               // indices 0..124
        Sv[tid] = 0.0f; Si[tid] = 0.0f;           // row 0
        Sv[tid * RD] = 0.0f; Si[tid * RD] = 0.0f; // col 0
    }
    __syncthreads();

    // ---- 4. row-wise inclusive scans over cols 1..124 (rows 1..124, both maps)
    for (int t = wid; t < 2 * NE; t += 16) {
        float* buf = (t < NE) ? Sv : Si;
        int rr = (t < NE ? t : t - NE) + 1;
        float* row = buf + rr * RD;
        float x0 = row[1 + lane];
        x0 = wscan(x0, lane);
        float c = __shfl(x0, 63, 64);
        float x1 = (lane < NE - 64) ? row[65 + lane] : 0.0f;
        x1 = wscan(x1, lane) + c;
        row[1 + lane] = x0;
        if (lane < NE - 64) row[65 + lane] = x1;
    }
    __syncthreads();

    // ---- 5. column-wise inclusive scans over rows 1..124 (cols 1..124)
    for (int t = wid; t < 2 * NE; t += 16) {
        float* buf = (t < NE) ? Sv : Si;
        int cc = (t < NE ? t : t - NE) + 1;
        float x0 = buf[(1 + lane) * RD + cc];
        x0 = wscan(x0, lane);
        float c = __shfl(x0, 63, 64);
        float x1 = (lane < NE - 64) ? buf[(65 + lane) * RD + cc] : 0.0f;
        x1 = wscan(x1, lane) + c;
        buf[(1 + lane) * RD + cc] = x0;
        if (lane < NE - 64) buf[(65 + lane) * RD + cc] = x1;
    }
    __syncthreads();

    // ---- 6. consume: 3 Sobels + 5-window SAT gather + residual
    const int radii[5] = {1, 3, 7, 15, 30};
    const float iw2[5] = {1.0f / 9.0f, 1.0f / 49.0f, 1.0f / 225.0f,
                          1.0f / 961.0f, 1.0f / 3721.0f};
    double acc = 0.0;
    const int ox = tid & 63;       // == lane
    const int oy0 = tid >> 6;      // == wid
    #pragma unroll
    for (int oi = 0; oi < 4; ++oi) {
        int oy = oi * 16 + oy0;
        int y = ty * TS + oy, x = tx * TS + ox;
        float gvx, gvy, gix, giy, gfx, gfy;
        sobel_g(pv, y, x, gvx, gvy);
        sobel_g(pi, y, x, gix, giy);
        sobel_g(pf, y, x, gfx, gfy);
        float a = 0.0f;
        #pragma unroll
        for (int k = 0; k < 5; ++k) {
            const int r = radii[k];
            int j0 = oy + 30 - r, j1 = oy + 31 + r;
            int i0 = ox + 30 - r, i1 = ox + 31 + r;
            float sv = Sv[j1 * RD + i1] - Sv[j0 * RD + i1]
                     - Sv[j1 * RD + i0] + Sv[j0 * RD + i0];
            float si = Si[j1 * RD + i1] - Si[j0 * RD + i1]
                     - Si[j1 * RD + i0] + Si[j0 * RD + i0];
            float evv = sv * iw2[k], eii = si * iw2[k];
            float wt = evv / (evv + eii + 1e-8f);
            float txv = gix + wt * (gvx - gix);
            float tyv = giy + wt * (gvy - giy);
            float dx = gfx - txv, dy = gfy - tyv;
            a += dx * dx + dy * dy;
        }
        acc += (double)a;
    }

    // ---- 7. block reduce (f64, deterministic)
    #pragma unroll
    for (int off = 32; off > 0; off >>= 1) acc += __shfl_down(acc, off, 64);
    if (lane == 0) red[wid] = acc;
    __syncthreads();
    if (wid == 0) {
        double s = (lane < 16) ? red[lane] : 0.0;
        #pragma unroll
        for (int off = 8; off > 0; off >>= 1) s += __shfl_down(s, off, 64);
        if (lane == 0)
            partials[((size_t)blockIdx.z * 8 + blockIdx.y) * 8 + blockIdx.x] = s;
    }
}

__global__ __launch_bounds__(256) void k_reduce(const double* __restrict__ partials,
                                                int np, float* __restrict__ out) {
    __shared__ double red[256];
    double s = 0.0;
    for (int idx = threadIdx.x; idx < np; idx += 256) s += partials[idx];
    red[threadIdx.x] = s;
    __syncthreads();
    #pragma unroll
    for (int t = 128; t > 0; t >>= 1) {
        if (threadIdx.x < t) red[threadIdx.x] += red[threadIdx.x + t];
        __syncthreads();
    }
    if (threadIdx.x == 0)
        out[0] = (float)(red[0] / (double)((size_t)NIMG * H * W));
}

extern "C" void kernel_launch(void* const* d_in, const int* in_sizes, int n_in,
                              void* d_out, int out_size, void* d_ws, size_t ws_size,
                              hipStream_t stream) {
    const float* v   = (const float*)d_in[0];
    const float* i_  = (const float*)d_in[1];
    const float* img = (const float*)d_in[2];
    float* out = (float*)d_out;

    double* partials = (double*)d_ws;           // 512 doubles
    k_tile<<<dim3(W / TS, H / TS, NIMG), dim3(1024), 0, stream>>>(v, i_, img, partials);
    k_reduce<<<dim3(1), dim3(256), 0, stream>>>(partials, 512, out);
}

// Round 3
// 98.562 us; speedup vs baseline: 1.6677x; 1.6677x over previous
//
#include <hip/hip_runtime.h>

#define H 512
#define W 512
#define NIMG 8
#define SW 513                    // SAT dimension (H+1)
#define SAT_PER (SW * SW)         // floats per map SAT

// zero-padded global load ('SAME' conv padding)
__device__ __forceinline__ float ldz(const float* __restrict__ p, int y, int x) {
    return ((unsigned)y < (unsigned)H && (unsigned)x < (unsigned)W) ? p[y * W + x] : 0.0f;
}

// Sobel (cross-correlation, matches lax.conv):
__device__ __forceinline__ void sobel_g(const float* __restrict__ p, int y, int x,
                                        float& gx, float& gy) {
    float a00 = ldz(p, y - 1, x - 1), a01 = ldz(p, y - 1, x), a02 = ldz(p, y - 1, x + 1);
    float a10 = ldz(p, y,     x - 1),                          a12 = ldz(p, y,     x + 1);
    float a20 = ldz(p, y + 1, x - 1), a21 = ldz(p, y + 1, x), a22 = ldz(p, y + 1, x + 1);
    gx = (a02 - a00) + 2.0f * (a12 - a10) + (a22 - a20);
    gy = (a20 - a00) + 2.0f * (a21 - a01) + (a22 - a02);
}

// ---- kernel 1: Sobel energy + row-inclusive prefix (f32, shuffle scan) ---
// Writes exclusive-SAT row y+1: row[x+1] = prefix_x(E[y][0..x]), row[0]=0.
__global__ __launch_bounds__(512) void k_rowscan(const float* __restrict__ v,
                                                 const float* __restrict__ i_,
                                                 float* __restrict__ sat) {
    const int x = threadIdx.x;   // 0..511
    const int y = blockIdx.x;
    const int n = blockIdx.y;
    const int m = blockIdx.z;
    const float* src = (m == 0 ? v : i_) + (size_t)n * (H * W);

    float gx, gy;
    sobel_g(src, y, x, gx, gy);
    float e = gx * gx + gy * gy;

    const int lane = x & 63, wid = x >> 6;
    float s = e;
    #pragma unroll
    for (int off = 1; off < 64; off <<= 1) {
        float t = __shfl_up(s, off, 64);
        if (lane >= off) s += t;
    }
    __shared__ float wt[8];
    if (lane == 63) wt[wid] = s;
    __syncthreads();
    float o = 0.0f;
    for (int w2 = 0; w2 < wid; ++w2) o += wt[w2];   // uniform within wave
    float incl = s + o;

    float* row = sat + (size_t)(n * 2 + m) * SAT_PER + (size_t)(y + 1) * SW;
    row[x + 1] = incl;
    if (x == 0) row[0] = 0.0f;
}

// ---- kernel 2: column running sum (in place, coalesced) ------------------
__global__ __launch_bounds__(256) void k_colscan(float* __restrict__ sat) {
    const int c = blockIdx.x * 256 + threadIdx.x;
    if (c >= SW) return;
    float* base = sat + (size_t)blockIdx.y * SAT_PER;
    base[c] = 0.0f;                 // SAT row 0 = zeros
    float run = 0.0f;
    #pragma unroll 4
    for (int y = 1; y <= H; ++y) {
        float t = base[(size_t)y * SW + c];
        run += t;
        base[(size_t)y * SW + c] = run;
    }
}

// ---- kernel 3: fused Sobel + 5-window SAT gather + residual --------------
// 1-D grid, n = bid & 7 so each image's SAT pair stays in one XCD's L2.
__global__ __launch_bounds__(256) void k_main(const float* __restrict__ v,
                                              const float* __restrict__ i_,
                                              const float* __restrict__ img,
                                              const float* __restrict__ sat,
                                              double* __restrict__ partials) {
    const int bid = blockIdx.x;
    const int n = bid & 7;
    const int t = bid >> 3;               // 0..1023
    const int x = (t & 7) * 64 + (threadIdx.x & 63);
    const int y = (t >> 3) * 4 + (threadIdx.x >> 6);

    const float* pv = v   + (size_t)n * (H * W);
    const float* pi = i_  + (size_t)n * (H * W);
    const float* pf = img + (size_t)n * (H * W);

    float gvx, gvy, gix, giy, gfx, gfy;
    sobel_g(pv, y, x, gvx, gvy);
    sobel_g(pi, y, x, gix, giy);
    sobel_g(pf, y, x, gfx, gfy);

    const float* Sv = sat + (size_t)(n * 2 + 0) * SAT_PER;
    const float* Si = sat + (size_t)(n * 2 + 1) * SAT_PER;

    const int   radii[5] = {1, 3, 7, 15, 30};
    const float iw2[5]   = {1.0f / 9.0f, 1.0f / 49.0f, 1.0f / 225.0f,
                            1.0f / 961.0f, 1.0f / 3721.0f};

    float acc = 0.0f;
    #pragma unroll
    for (int k = 0; k < 5; ++k) {
        const int r  = radii[k];
        const int y0 = max(y - r, 0), y1 = min(y + r + 1, H);
        const int x0 = max(x - r, 0), x1 = min(x + r + 1, W);
        float sv = Sv[(size_t)y1 * SW + x1] - Sv[(size_t)y0 * SW + x1]
                 - Sv[(size_t)y1 * SW + x0] + Sv[(size_t)y0 * SW + x0];
        float si = Si[(size_t)y1 * SW + x1] - Si[(size_t)y0 * SW + x1]
                 - Si[(size_t)y1 * SW + x0] + Si[(size_t)y0 * SW + x0];
        float ev = sv * iw2[k];
        float ei = si * iw2[k];
        float wtt = ev / (ev + ei + 1e-8f);
        float tx = gix + wtt * (gvx - gix);   // wt*gvx + (1-wt)*gix
        float ty = giy + wtt * (gvy - giy);
        float dx = gfx - tx, dy = gfy - ty;
        acc += dx * dx + dy * dy;
    }

    // block reduction (f64, deterministic)
    double a = (double)acc;
    const int lane = threadIdx.x & 63, wid = threadIdx.x >> 6;
    #pragma unroll
    for (int off = 32; off > 0; off >>= 1) a += __shfl_down(a, off, 64);
    __shared__ double red[4];
    if (lane == 0) red[wid] = a;
    __syncthreads();
    if (threadIdx.x == 0)
        partials[bid] = red[0] + red[1] + red[2] + red[3];
}

// ---- kernel 4: final reduce ----------------------------------------------
__global__ __launch_bounds__(256) void k_reduce(const double* __restrict__ partials,
                                                int np, float* __restrict__ out) {
    __shared__ double red[256];
    double s = 0.0;
    for (int idx = threadIdx.x; idx < np; idx += 256) s += partials[idx];
    red[threadIdx.x] = s;
    __syncthreads();
    #pragma unroll
    for (int t = 128; t > 0; t >>= 1) {
        if (threadIdx.x < t) red[threadIdx.x] += red[threadIdx.x + t];
        __syncthreads();
    }
    if (threadIdx.x == 0)
        out[0] = (float)(red[0] / (double)((size_t)NIMG * H * W));
}

// ---- launch --------------------------------------------------------------

extern "C" void kernel_launch(void* const* d_in, const int* in_sizes, int n_in,
                              void* d_out, int out_size, void* d_ws, size_t ws_size,
                              hipStream_t stream) {
    const float* v   = (const float*)d_in[0];
    const float* i_  = (const float*)d_in[1];
    const float* img = (const float*)d_in[2];
    float* out = (float*)d_out;

    float* sat       = (float*)d_ws;                       // 16 * 513*513 f32 = 16.8 MB
    double* partials = (double*)(sat + (size_t)16 * SAT_PER);  // 8192 f64

    k_rowscan<<<dim3(512, NIMG, 2), dim3(512), 0, stream>>>(v, i_, sat);
    k_colscan<<<dim3(3, 16), dim3(256), 0, stream>>>(sat);
    k_main<<<dim3(8192), dim3(256), 0, stream>>>(v, i_, img, sat, partials);
    k_reduce<<<dim3(1), dim3(256), 0, stream>>>(partials, 8192, out);
}

// Round 4
// 69.306 us; speedup vs baseline: 2.3717x; 1.4221x over previous
//
#include <hip/hip_runtime.h>

#define H 512
#define W 512
#define NIMG 8
#define SW 513                    // SAT dimension (H+1)
#define SAT_PER (SW * SW)         // floats per map SAT
#define NB 8                      // column-scan bands
#define BR 64                     // rows per band (NB*BR == H)

// zero-padded global load ('SAME' conv padding)
__device__ __forceinline__ float ldz(const float* __restrict__ p, int y, int x) {
    return ((unsigned)y < (unsigned)H && (unsigned)x < (unsigned)W) ? p[y * W + x] : 0.0f;
}

// Sobel (cross-correlation, matches lax.conv):
__device__ __forceinline__ void sobel_g(const float* __restrict__ p, int y, int x,
                                        float& gx, float& gy) {
    float a00 = ldz(p, y - 1, x - 1), a01 = ldz(p, y - 1, x), a02 = ldz(p, y - 1, x + 1);
    float a10 = ldz(p, y,     x - 1),                          a12 = ldz(p, y,     x + 1);
    float a20 = ldz(p, y + 1, x - 1), a21 = ldz(p, y + 1, x), a22 = ldz(p, y + 1, x + 1);
    gx = (a02 - a00) + 2.0f * (a12 - a10) + (a22 - a20);
    gy = (a20 - a00) + 2.0f * (a21 - a01) + (a22 - a02);
}

// ---- kernel 1: Sobel energy + row-inclusive prefix (f32, shuffle scan) ---
__global__ __launch_bounds__(512) void k_rowscan(const float* __restrict__ v,
                                                 const float* __restrict__ i_,
                                                 float* __restrict__ sat) {
    const int x = threadIdx.x;   // 0..511
    const int y = blockIdx.x;
    const int n = blockIdx.y;
    const int m = blockIdx.z;
    const float* src = (m == 0 ? v : i_) + (size_t)n * (H * W);

    float gx, gy;
    sobel_g(src, y, x, gx, gy);
    float e = gx * gx + gy * gy;

    const int lane = x & 63, wid = x >> 6;
    float s = e;
    #pragma unroll
    for (int off = 1; off < 64; off <<= 1) {
        float t = __shfl_up(s, off, 64);
        if (lane >= off) s += t;
    }
    __shared__ float wt[8];
    if (lane == 63) wt[wid] = s;
    __syncthreads();
    float o = 0.0f;
    for (int w2 = 0; w2 < wid; ++w2) o += wt[w2];   // uniform within wave
    float incl = s + o;

    float* row = sat + (size_t)(n * 2 + m) * SAT_PER + (size_t)(y + 1) * SW;
    row[x + 1] = incl;
    if (x == 0) row[0] = 0.0f;
}

// ---- kernel 2a: per-band column sums (read-only) -------------------------
// bandsum[map][band][c] = sum of sat[map][1+band*BR .. (band+1)*BR][c]
__global__ __launch_bounds__(256) void k_bandsum(const float* __restrict__ sat,
                                                 float* __restrict__ bandsum) {
    const int c = blockIdx.x * 256 + threadIdx.x;
    if (c >= SW) return;
    const int b = blockIdx.y, map = blockIdx.z;
    const float* base = sat + (size_t)map * SAT_PER + (size_t)(1 + b * BR) * SW + c;
    float s = 0.0f;
    #pragma unroll
    for (int r = 0; r < BR; ++r) s += base[(size_t)r * SW];
    bandsum[((size_t)map * NB + b) * SW + c] = s;
}

// ---- kernel 2b: exclusive scan of band sums (in place) -------------------
__global__ __launch_bounds__(256) void k_bandscan(float* __restrict__ bandsum) {
    const int idx = blockIdx.x * 256 + threadIdx.x;   // (map, c) pair
    const int map = idx / SW, c = idx % SW;
    if (map >= 2 * NIMG) return;
    float* bs = bandsum + (size_t)map * NB * SW + c;
    float run = 0.0f;
    #pragma unroll
    for (int b = 0; b < NB; ++b) {
        float t = bs[(size_t)b * SW];
        bs[(size_t)b * SW] = run;
        run += t;
    }
}

// ---- kernel 2c: band-local running sum seeded by offset (in place) -------
__global__ __launch_bounds__(256) void k_bandapply(float* __restrict__ sat,
                                                   const float* __restrict__ bandsum) {
    const int c = blockIdx.x * 256 + threadIdx.x;
    if (c >= SW) return;
    const int b = blockIdx.y, map = blockIdx.z;
    float* base = sat + (size_t)map * SAT_PER + (size_t)(1 + b * BR) * SW + c;
    if (b == 0) sat[(size_t)map * SAT_PER + c] = 0.0f;   // SAT row 0 = zeros
    float run = bandsum[((size_t)map * NB + b) * SW + c];
    #pragma unroll 4
    for (int r = 0; r < BR; ++r) {
        float t = base[(size_t)r * SW];
        run += t;
        base[(size_t)r * SW] = run;
    }
}

// ---- kernel 3: fused Sobel + 5-window SAT gather + residual --------------
// 1-D grid, n = bid & 7 so each image's SAT pair stays in one XCD's L2.
__global__ __launch_bounds__(256) void k_main(const float* __restrict__ v,
                                              const float* __restrict__ i_,
                                              const float* __restrict__ img,
                                              const float* __restrict__ sat,
                                              double* __restrict__ partials) {
    const int bid = blockIdx.x;
    const int n = bid & 7;
    const int t = bid >> 3;               // 0..1023
    const int x = (t & 7) * 64 + (threadIdx.x & 63);
    const int y = (t >> 3) * 4 + (threadIdx.x >> 6);

    const float* pv = v   + (size_t)n * (H * W);
    const float* pi = i_  + (size_t)n * (H * W);
    const float* pf = img + (size_t)n * (H * W);

    float gvx, gvy, gix, giy, gfx, gfy;
    sobel_g(pv, y, x, gvx, gvy);
    sobel_g(pi, y, x, gix, giy);
    sobel_g(pf, y, x, gfx, gfy);

    const float* Sv = sat + (size_t)(n * 2 + 0) * SAT_PER;
    const float* Si = sat + (size_t)(n * 2 + 1) * SAT_PER;

    const int   radii[5] = {1, 3, 7, 15, 30};
    const float iw2[5]   = {1.0f / 9.0f, 1.0f / 49.0f, 1.0f / 225.0f,
                            1.0f / 961.0f, 1.0f / 3721.0f};

    float acc = 0.0f;
    #pragma unroll
    for (int k = 0; k < 5; ++k) {
        const int r  = radii[k];
        const int y0 = max(y - r, 0), y1 = min(y + r + 1, H);
        const int x0 = max(x - r, 0), x1 = min(x + r + 1, W);
        float sv = Sv[(size_t)y1 * SW + x1] - Sv[(size_t)y0 * SW + x1]
                 - Sv[(size_t)y1 * SW + x0] + Sv[(size_t)y0 * SW + x0];
        float si = Si[(size_t)y1 * SW + x1] - Si[(size_t)y0 * SW + x1]
                 - Si[(size_t)y1 * SW + x0] + Si[(size_t)y0 * SW + x0];
        float ev = sv * iw2[k];
        float ei = si * iw2[k];
        float wtt = ev / (ev + ei + 1e-8f);
        float tx = gix + wtt * (gvx - gix);   // wt*gvx + (1-wt)*gix
        float ty = giy + wtt * (gvy - giy);
        float dx = gfx - tx, dy = gfy - ty;
        acc += dx * dx + dy * dy;
    }

    // block reduction (f64, deterministic)
    double a = (double)acc;
    const int lane = threadIdx.x & 63, wid = threadIdx.x >> 6;
    #pragma unroll
    for (int off = 32; off > 0; off >>= 1) a += __shfl_down(a, off, 64);
    __shared__ double red[4];
    if (lane == 0) red[wid] = a;
    __syncthreads();
    if (threadIdx.x == 0)
        partials[bid] = red[0] + red[1] + red[2] + red[3];
}

// ---- kernel 4: final reduce ----------------------------------------------
__global__ __launch_bounds__(256) void k_reduce(const double* __restrict__ partials,
                                                int np, float* __restrict__ out) {
    __shared__ double red[256];
    double s = 0.0;
    for (int idx = threadIdx.x; idx < np; idx += 256) s += partials[idx];
    red[threadIdx.x] = s;
    __syncthreads();
    #pragma unroll
    for (int t = 128; t > 0; t >>= 1) {
        if (threadIdx.x < t) red[threadIdx.x] += red[threadIdx.x + t];
        __syncthreads();
    }
    if (threadIdx.x == 0)
        out[0] = (float)(red[0] / (double)((size_t)NIMG * H * W));
}

// ---- launch --------------------------------------------------------------

extern "C" void kernel_launch(void* const* d_in, const int* in_sizes, int n_in,
                              void* d_out, int out_size, void* d_ws, size_t ws_size,
                              hipStream_t stream) {
    const float* v   = (const float*)d_in[0];
    const float* i_  = (const float*)d_in[1];
    const float* img = (const float*)d_in[2];
    float* out = (float*)d_out;

    float* sat       = (float*)d_ws;                           // 16 * 513*513 f32 = 16.8 MB
    float* bandsum   = sat + (size_t)16 * SAT_PER;             // 16 * 8 * 513 f32
    double* partials = (double*)(bandsum + (size_t)16 * NB * SW);  // 8192 f64

    k_rowscan<<<dim3(512, NIMG, 2), dim3(512), 0, stream>>>(v, i_, sat);
    k_bandsum<<<dim3(3, NB, 16), dim3(256), 0, stream>>>(sat, bandsum);
    k_bandscan<<<dim3((2 * NIMG * SW + 255) / 256), dim3(256), 0, stream>>>(bandsum);
    k_bandapply<<<dim3(3, NB, 16), dim3(256), 0, stream>>>(sat, bandsum);
    k_main<<<dim3(8192), dim3(256), 0, stream>>>(v, i_, img, sat, partials);
    k_reduce<<<dim3(1), dim3(256), 0, stream>>>(partials, 8192, out);
}